// Round 6
// baseline (710.275 us; speedup 1.0000x reference)
//
#include <hip/hip_runtime.h>
#include <hip/hip_bf16.h>
#include <math.h>

typedef __hip_bfloat16 hbf16;
typedef __attribute__((ext_vector_type(8))) short bf16x8;
typedef __attribute__((ext_vector_type(4))) float f32x4;

constexpr int kD  = 1024;
constexpr int kP  = 512;
constexpr int kH  = 16;
constexpr int kFF = 4096;
constexpr int kHD = 64;
constexpr int kB  = 2;
constexpr int kL  = 1024;
constexpr int kTok = kB * kL;   // 2048

__device__ inline short f2bf(float x) { hbf16 h = __float2bfloat16(x); return *(short*)&h; }

__device__ __forceinline__ void gload16(const void* g, void* l) {
    __builtin_amdgcn_global_load_lds(
        (const __attribute__((address_space(1))) void*)g,
        (__attribute__((address_space(3))) void*)l, 16, 0, 0);
}

// ---------------- fp32 -> bf16 cast ----------------
__global__ __launch_bounds__(256) void cast_bf16(
    const float* __restrict__ in, short* __restrict__ out, int total4)
{
    int i = blockIdx.x * 256 + threadIdx.x;
    if (i >= total4) return;
    float4 v = *(const float4*)&in[(size_t)i * 4];
    *(short4*)&out[(size_t)i * 4] = make_short4(f2bf(v.x), f2bf(v.y), f2bf(v.z), f2bf(v.w));
}

// ---------------- weight transpose+convert: fp32 [K][N] -> bf16-bits [N][K] ----------------
__global__ __launch_bounds__(256) void transpose_bf16(
    const float* __restrict__ src, short* __restrict__ dst, int K, int N)
{
    __shared__ float t[32][33];
    int n0 = blockIdx.x * 32, k0 = blockIdx.y * 32;
    int tx = threadIdx.x & 31, ty = threadIdx.x >> 5;
    #pragma unroll
    for (int r = ty; r < 32; r += 8)
        t[r][tx] = src[(size_t)(k0 + r) * N + n0 + tx];
    __syncthreads();
    #pragma unroll
    for (int r = ty; r < 32; r += 8)
        dst[(size_t)(n0 + r) * K + k0 + tx] = f2bf(t[tx][r]);
}

// ---------------- bias broadcast fill: C[m][n] = bias[n] (N power of two) ----------------
__global__ __launch_bounds__(256) void bias_fill(
    const float* __restrict__ bias, float* __restrict__ C, int N, int total4)
{
    int i = blockIdx.x * 256 + threadIdx.x;
    if (i >= total4) return;
    int n = (i * 4) & (N - 1);
    *(float4*)&C[(size_t)i * 4] = *(const float4*)&bias[n];
}

// ---------------- concat up to 3 bias vectors of length n ----------------
__global__ void concat_bias(float* __restrict__ o, const float* __restrict__ a,
                            const float* __restrict__ b, const float* __restrict__ c, int n)
{
    int i = blockIdx.x * blockDim.x + threadIdx.x;
    if (i < n) o[i] = a[i];
    else if (i < 2 * n) { if (b) o[i] = b[i - n]; }
    else if (i < 3 * n) { if (c) o[i] = c[i - 2 * n]; }
}

// ---------------- MFMA GEMM: bf16 A/B, fragment-ordered DMA staging, dbuf pipeline ----------------
// LDS layout per 128x32 tile: 8 groups of (16 rows x 32 shorts) = 1024 B each, stored
// fragment-ordered: element (row r, quad q) of group g at shorts [g*512 + q*128 + (r&15)*8].
// Lane l stages global row (base + l&15), quad (l>>4); DMA dest = groupbase + l*16 B (linear).
// Fragment read: lane l reads &buf[g*512 + l*8] -> 64 lanes = 1024 contiguous B, conflict-free.
__global__ __launch_bounds__(256) void gemm_mfma(
    const short* __restrict__ A, const short* __restrict__ WT,
    const float* __restrict__ bias, float* __restrict__ C, short* __restrict__ C16,
    int M, int N, int K, int act, int ksplit)
{
    __shared__ short As[2][4096];
    __shared__ short Bs[2][4096];
    const int tid = threadIdx.x;

    // bijective XCD-aware swizzle over linearized (x,y) grid
    const int gx = gridDim.x;
    const int nwg = gx * gridDim.y;
    const int orig = blockIdx.y * gx + blockIdx.x;
    const int qq = nwg >> 3, rr = nwg & 7;
    const int xcd = orig & 7, lid = orig >> 3;
    const int swz = (xcd < rr) ? (xcd * (qq + 1) + lid)
                               : (rr * (qq + 1) + (xcd - rr) * qq + lid);
    const int m0 = (swz / gx) * 128, n0 = (swz % gx) * 128;

    const int ks = K / ksplit;
    const int kbeg = blockIdx.z * ks, kend = kbeg + ks;
    const int wave = tid >> 6, lane = tid & 63;
    const int l15 = lane & 15, quad = lane >> 4;
    const int wm = (wave & 1) * 64, wn = (wave >> 1) * 64;

    // staging source coords (fragment-ordered): row-in-group, short-col
    const int sgr = lane & 15;
    const int sgq = (lane >> 4) * 8;
    // wave stages groups 2*wave (rows +0..15) and 2*wave+1 (rows +16..31)
    const size_t arow0 = (size_t)(m0 + wave * 32 + sgr) * K + sgq;
    const size_t arow1 = arow0 + (size_t)16 * K;
    const size_t brow0 = (size_t)(n0 + wave * 32 + sgr) * K + sgq;
    const size_t brow1 = brow0 + (size_t)16 * K;

    f32x4 acc[4][4];
    #pragma unroll
    for (int i = 0; i < 4; ++i)
        #pragma unroll
        for (int j = 0; j < 4; ++j)
            acc[i][j] = (f32x4){0.f, 0.f, 0.f, 0.f};

    // prologue: stage first tile into buf 0
    gload16(&A [arow0 + kbeg], &As[0][(wave * 2) * 512]);
    gload16(&A [arow1 + kbeg], &As[0][(wave * 2 + 1) * 512]);
    gload16(&WT[brow0 + kbeg], &Bs[0][(wave * 2) * 512]);
    gload16(&WT[brow1 + kbeg], &Bs[0][(wave * 2 + 1) * 512]);
    __syncthreads();

    const int ga = (wave & 1) * 4, gb = (wave >> 1) * 4;
    int cur = 0;
    for (int kk = kbeg; kk < kend; kk += 32) {
        // prefetch next K-tile into the other buffer (overlaps with compute below)
        if (kk + 32 < kend) {
            int nxt = cur ^ 1;
            gload16(&A [arow0 + kk + 32], &As[nxt][(wave * 2) * 512]);
            gload16(&A [arow1 + kk + 32], &As[nxt][(wave * 2 + 1) * 512]);
            gload16(&WT[brow0 + kk + 32], &Bs[nxt][(wave * 2) * 512]);
            gload16(&WT[brow1 + kk + 32], &Bs[nxt][(wave * 2 + 1) * 512]);
        }

        bf16x8 af[4], bfr[4];
        #pragma unroll
        for (int i = 0; i < 4; ++i)
            af[i] = *(bf16x8*)&As[cur][(ga + i) * 512 + lane * 8];
        #pragma unroll
        for (int j = 0; j < 4; ++j)
            bfr[j] = *(bf16x8*)&Bs[cur][(gb + j) * 512 + lane * 8];
        #pragma unroll
        for (int i = 0; i < 4; ++i)
            #pragma unroll
            for (int j = 0; j < 4; ++j)
                acc[i][j] = __builtin_amdgcn_mfma_f32_16x16x32_bf16(af[i], bfr[j], acc[i][j], 0, 0, 0);
        __syncthreads();   // reads of buf[cur] done; DMA for buf[cur^1] drained
        cur ^= 1;
    }

    #pragma unroll
    for (int j = 0; j < 4; ++j) {
        int n = n0 + wn + j * 16 + l15;
        if (ksplit == 1) {
            float bv = bias[n];
            #pragma unroll
            for (int i = 0; i < 4; ++i) {
                int mb = m0 + wm + i * 16 + quad * 4;
                #pragma unroll
                for (int r = 0; r < 4; ++r) {
                    float v = acc[i][j][r] + bv;
                    if (act) v = v * 0.5f * (1.0f + erff(v * 0.70710678118654752f));
                    if (C)   C[(size_t)(mb + r) * N + n] = v;
                    if (C16) C16[(size_t)(mb + r) * N + n] = f2bf(v);
                }
            }
        } else {
            #pragma unroll
            for (int i = 0; i < 4; ++i) {
                int mb = m0 + wm + i * 16 + quad * 4;
                #pragma unroll
                for (int r = 0; r < 4; ++r)
                    atomicAdd(&C[(size_t)(mb + r) * N + n], acc[i][j][r]);
            }
        }
    }
}

// ---------------- qk_pack: RoPE + optional scale + bf16 cast, [Tok,ldx] -> [b,h,l,64] ----------------
__global__ void qk_pack(const float* __restrict__ x, const float* __restrict__ pos,
                        short* __restrict__ outp, float scale, int ldx, int off)
{
    int idx = blockIdx.x * blockDim.x + threadIdx.x;
    if (idx >= kTok * kH * 32) return;
    int d = idx & 31;
    int h = (idx >> 5) & (kH - 1);
    int row = idx >> 9;
    int l = row & (kL - 1);
    int b = row >> 10;
    float a1 = pos[l * kHD + d];
    float a2 = pos[l * kHD + d + 32];
    size_t base = (size_t)row * ldx + off + h * kHD;
    float x1 = x[base + d], x2 = x[base + d + 32];
    float r1 = (x1 * cosf(a1) - x2 * sinf(a1)) * scale;
    float r2 = (x2 * cosf(a2) + x1 * sinf(a2)) * scale;
    size_t ob = ((size_t)(b * kH + h) * kL + l) * 64;
    outp[ob + d]      = f2bf(r1);
    outp[ob + d + 32] = f2bf(r2);
}

// ---------------- v_pack: transpose [Tok,ldx] fp32 -> [b,h,hd,l] bf16 ----------------
__global__ __launch_bounds__(256) void v_pack(const float* __restrict__ v, short* __restrict__ outp,
                                              int ldx, int off)
{
    int l0 = blockIdx.x * 64, h = blockIdx.y, b = blockIdx.z;
    __shared__ float t[64][65];
    int tid = threadIdx.x;
    #pragma unroll
    for (int e = 0; e < 4; ++e) {
        int idx = tid + e * 256;
        int r = idx >> 4, c4 = (idx & 15) * 4;
        const float4 vv = *(const float4*)&v[(size_t)(b * kL + l0 + r) * ldx + off + h * kHD + c4];
        t[r][c4] = vv.x; t[r][c4 + 1] = vv.y; t[r][c4 + 2] = vv.z; t[r][c4 + 3] = vv.w;
    }
    __syncthreads();
    int hd = tid >> 2, seg = (tid & 3) * 16;
    size_t ob = ((size_t)(b * kH + h) * 64 + hd) * kL + l0 + seg;
    short tmp[16];
    #pragma unroll
    for (int i = 0; i < 16; ++i) tmp[i] = f2bf(t[seg + i][hd]);
    #pragma unroll
    for (int i = 0; i < 16; i += 4)
        *(short4*)&outp[ob + i] = make_short4(tmp[i], tmp[i + 1], tmp[i + 2], tmp[i + 3]);
}

// ---------------- MFMA flash attention (fragment-ordered LDS, staged alibi; bf16 out) ----------------
constexpr int AQ = 64, AK = 64;
__global__ __launch_bounds__(256, 2) void attn_mfma(
    const short* __restrict__ qpk, const short* __restrict__ kpk,
    const short* __restrict__ vpk, const float* __restrict__ alibi,
    const int* __restrict__ mask, short* __restrict__ out)
{
    const int q0 = blockIdx.x * AQ, h = blockIdx.y, b = blockIdx.z;
    const int tid = threadIdx.x, wave = tid >> 6, lane = tid & 63;
    const int l15 = lane & 15, quad = lane >> 4;
    __shared__ short Qf[4096];
    __shared__ short Kf[4096];
    __shared__ short Vf[4096];
    __shared__ float ALPS[4 * 1088];

    const short* qbase = qpk + ((size_t)(b * kH + h) * kL) * 64;
    const short* kbase = kpk + ((size_t)(b * kH + h) * kL) * 64;
    const short* vbase = vpk + ((size_t)(b * kH + h) * 64) * kL;
    const float* abase = alibi + ((size_t)h * kL + q0) * kL;
    const int*   mbase = mask + b * kL;

    const int sr = tid >> 3, sc8 = (tid & 7) * 8;
    const int sQuad = (sc8 >> 3) & 3, sS = sc8 >> 5;
    const int ar = tid >> 4, ac4 = (tid & 15) * 4;

    #pragma unroll
    for (int e = 0; e < 2; ++e) {
        int r = sr + e * 32;
        int slot = ((r >> 4) * 2 + sS) * 512 + (r & 15) * 32 + sQuad * 8;
        *(bf16x8*)&Qf[slot] = *(const bf16x8*)&qbase[(size_t)(q0 + r) * 64 + sc8];
    }

    bf16x8 rk[2], rv[2];
    float4 ral[4];
    int4 rmk;
    auto load_tile = [&](int k0) {
        #pragma unroll
        for (int e = 0; e < 2; ++e) {
            int r = sr + e * 32;
            rk[e] = *(const bf16x8*)&kbase[(size_t)(k0 + r) * 64 + sc8];
            rv[e] = *(const bf16x8*)&vbase[(size_t)r * kL + k0 + sc8];
        }
        #pragma unroll
        for (int e = 0; e < 4; ++e)
            ral[e] = *(const float4*)&abase[(size_t)(ar + e * 16) * kL + k0 + ac4];
        rmk = *(const int4*)&mbase[k0 + ac4];
    };
    auto store_tile = [&]() {
        #pragma unroll
        for (int e = 0; e < 2; ++e) {
            int r = sr + e * 32;
            int slot = ((r >> 4) * 2 + sS) * 512 + (r & 15) * 32 + sQuad * 8;
            *(bf16x8*)&Kf[slot] = rk[e];
            *(bf16x8*)&Vf[slot] = rv[e];
        }
        #pragma unroll
        for (int e = 0; e < 4; ++e) {
            float4 a = ral[e];
            a.x = rmk.x ? -1e30f : a.x;
            a.y = rmk.y ? -1e30f : a.y;
            a.z = rmk.z ? -1e30f : a.z;
            a.w = rmk.w ? -1e30f : a.w;
            *(float4*)&ALPS[(ar + e * 16) * 68 + ac4] = a;
        }
    };

    float mst[4], lst[4];
    #pragma unroll
    for (int r = 0; r < 4; ++r) { mst[r] = -3e38f; lst[r] = 0.f; }
    f32x4 oacc[4];
    #pragma unroll
    for (int j = 0; j < 4; ++j) oacc[j] = (f32x4){0.f, 0.f, 0.f, 0.f};

    load_tile(0);
    __syncthreads();

    bf16x8 aq[2];
    #pragma unroll
    for (int s = 0; s < 2; ++s)
        aq[s] = *(bf16x8*)&Qf[(wave * 2 + s) * 512 + l15 * 32 + quad * 8];

    for (int t = 0; t < kL / AK; ++t) {
        store_tile();
        __syncthreads();
        if (t + 1 < kL / AK) load_tile((t + 1) * AK);

        f32x4 sacc[4];
        #pragma unroll
        for (int nt = 0; nt < 4; ++nt) sacc[nt] = (f32x4){0.f, 0.f, 0.f, 0.f};
        #pragma unroll
        for (int nt = 0; nt < 4; ++nt)
            #pragma unroll
            for (int s = 0; s < 2; ++s) {
                bf16x8 bk = *(bf16x8*)&Kf[(nt * 2 + s) * 512 + l15 * 32 + quad * 8];
                sacc[nt] = __builtin_amdgcn_mfma_f32_16x16x32_bf16(aq[s], bk, sacc[nt], 0, 0, 0);
            }

        float sv[4][4];
        float mx[4] = {-3e38f, -3e38f, -3e38f, -3e38f};
        #pragma unroll
        for (int nt = 0; nt < 4; ++nt)
            #pragma unroll
            for (int r = 0; r < 4; ++r) {
                float al = ALPS[(wave * 16 + quad * 4 + r) * 68 + nt * 16 + l15];
                float s = sacc[nt][r] + al;
                sv[nt][r] = s;
                mx[r] = fmaxf(mx[r], s);
            }
        #pragma unroll
        for (int m = 1; m <= 8; m <<= 1)
            #pragma unroll
            for (int r = 0; r < 4; ++r)
                mx[r] = fmaxf(mx[r], __shfl_xor(mx[r], m));
        float alpha[4], lsum[4];
        #pragma unroll
        for (int r = 0; r < 4; ++r) {
            float mn = fmaxf(mst[r], mx[r]);
            alpha[r] = __expf(mst[r] - mn);
            mst[r] = mn;
            lsum[r] = 0.f;
        }
        #pragma unroll
        for (int nt = 0; nt < 4; ++nt)
            #pragma unroll
            for (int r = 0; r < 4; ++r) {
                float p = __expf(sv[nt][r] - mst[r]);
                sv[nt][r] = p;
                lsum[r] += p;
            }
        #pragma unroll
        for (int m = 1; m <= 8; m <<= 1)
            #pragma unroll
            for (int r = 0; r < 4; ++r)
                lsum[r] += __shfl_xor(lsum[r], m);
        #pragma unroll
        for (int r = 0; r < 4; ++r) lst[r] = lst[r] * alpha[r] + lsum[r];

        #pragma unroll
        for (int nt = 0; nt < 4; ++nt)
            #pragma unroll
            for (int r = 0; r < 4; ++r)
                ALPS[wave * 1088 + (quad * 4 + r) * 67 + nt * 16 + l15] = sv[nt][r];
        #pragma unroll
        for (int j = 0; j < 4; ++j)
            #pragma unroll
            for (int r = 0; r < 4; ++r)
                oacc[j][r] *= alpha[r];

        #pragma unroll
        for (int s = 0; s < 2; ++s) {
            int pb = wave * 1088 + l15 * 67 + s * 32 + quad * 8;
            bf16x8 ap;
            #pragma unroll
            for (int e = 0; e < 8; ++e) ap[e] = f2bf(ALPS[pb + e]);
            #pragma unroll
            for (int j = 0; j < 4; ++j) {
                bf16x8 bv = *(bf16x8*)&Vf[(j * 2 + s) * 512 + l15 * 32 + quad * 8];
                oacc[j] = __builtin_amdgcn_mfma_f32_16x16x32_bf16(ap, bv, oacc[j], 0, 0, 0);
            }
        }
        __syncthreads();
    }

    #pragma unroll
    for (int j = 0; j < 4; ++j)
        #pragma unroll
        for (int r = 0; r < 4; ++r) {
            int qrow = q0 + wave * 16 + quad * 4 + r;
            out[(size_t)(b * kL + qrow) * kD + h * kHD + j * 16 + l15] = f2bf(oacc[j][r] / lst[r]);
        }
}

// ---------------- out = res + LayerNorm(z); also bf16 copy ----------------
__global__ __launch_bounds__(256) void add_ln(
    const float* __restrict__ res, const float* __restrict__ z,
    const float* __restrict__ g, const float* __restrict__ bi,
    float* __restrict__ out, short* __restrict__ out16)
{
    int row = blockIdx.x, tid = threadIdx.x;
    __shared__ float red[256], red2[256];
    const float* zr = z + (size_t)row * kD;
    float s = 0.f, sq = 0.f;
    for (int i = tid; i < kD; i += 256) { float vv = zr[i]; s += vv; sq += vv * vv; }
    red[tid] = s; red2[tid] = sq; __syncthreads();
    for (int st = 128; st > 0; st >>= 1) {
        if (tid < st) { red[tid] += red[tid + st]; red2[tid] += red2[tid + st]; }
        __syncthreads();
    }
    float mean = red[0] / kD;
    float var = red2[0] / kD - mean * mean;
    float rstd = rsqrtf(var + 1e-5f);
    for (int i = tid; i < kD; i += 256) {
        float vv = (zr[i] - mean) * rstd * g[i] + bi[i];
        float o = res[(size_t)row * kD + i] + vv;
        out[(size_t)row * kD + i] = o;
        out16[(size_t)row * kD + i] = f2bf(o);
    }
}

// ---------------- out = LayerNorm(res + f) ----------------
__global__ __launch_bounds__(256) void ln_final(
    const float* __restrict__ res, const float* __restrict__ f,
    const float* __restrict__ g, const float* __restrict__ bi,
    float* __restrict__ out)
{
    int row = blockIdx.x, tid = threadIdx.x;
    __shared__ float tt[kD];
    __shared__ float red[256], red2[256];
    float s = 0.f, sq = 0.f;
    for (int i = tid; i < kD; i += 256) {
        float vv = res[(size_t)row * kD + i] + f[(size_t)row * kD + i];
        tt[i] = vv; s += vv; sq += vv * vv;
    }
    red[tid] = s; red2[tid] = sq; __syncthreads();
    for (int st = 128; st > 0; st >>= 1) {
        if (tid < st) { red[tid] += red[tid + st]; red2[tid] += red2[tid + st]; }
        __syncthreads();
    }
    float mean = red[0] / kD;
    float var = red2[0] / kD - mean * mean;
    float rstd = rsqrtf(var + 1e-5f);
    for (int i = tid; i < kD; i += 256)
        out[(size_t)row * kD + i] = (tt[i] - mean) * rstd * g[i] + bi[i];
}

extern "C" void kernel_launch(void* const* d_in, const int* in_sizes, int n_in,
                              void* d_out, int out_size, void* d_ws, size_t ws_size,
                              hipStream_t stream)
{
    const float* memory      = (const float*)d_in[0];
    const float* tgt         = (const float*)d_in[1];
    const float* self_alibi  = (const float*)d_in[2];
    const float* self_pos    = (const float*)d_in[3];
    const float* cross_alibi = (const float*)d_in[4];
    const float* cross_pos   = (const float*)d_in[5];
    const int*   mask        = (const int*)d_in[6];
    const float* sa_lat_w = (const float*)d_in[7];   const float* sa_lat_b = (const float*)d_in[8];
    const float* sa_q_w   = (const float*)d_in[9];   const float* sa_q_b   = (const float*)d_in[10];
    const float* sa_k_w   = (const float*)d_in[11];  const float* sa_k_b   = (const float*)d_in[12];
    const float* sa_v_w   = (const float*)d_in[13];  const float* sa_v_b   = (const float*)d_in[14];
    const float* sa_out_w = (const float*)d_in[15];  const float* sa_out_b = (const float*)d_in[16];
    const float* ca_lat_w = (const float*)d_in[17];  const float* ca_lat_b = (const float*)d_in[18];
    const float* ca_q_w   = (const float*)d_in[19];  const float* ca_q_b   = (const float*)d_in[20];
    const float* ca_k_w   = (const float*)d_in[21];  const float* ca_k_b   = (const float*)d_in[22];
    const float* ca_v_w   = (const float*)d_in[23];  const float* ca_v_b   = (const float*)d_in[24];
    const float* ca_out_w = (const float*)d_in[25];  const float* ca_out_b = (const float*)d_in[26];
    const float* lin1_w   = (const float*)d_in[27];  const float* lin1_b   = (const float*)d_in[28];
    const float* lin2_w   = (const float*)d_in[29];  const float* lin2_b   = (const float*)d_in[30];
    const float* n1_g = (const float*)d_in[31];  const float* n1_b = (const float*)d_in[32];
    const float* n2_g = (const float*)d_in[33];  const float* n2_b = (const float*)d_in[34];
    const float* n3_g = (const float*)d_in[35];  const float* n3_b = (const float*)d_in[36];

    // workspace map (floats; M1 = 1M floats = 4 MB). Total 15M floats = 60 MB.
    const size_t M1 = 1u << 20;
    float* W      = (float*)d_ws;
    float* xb     = W;                              // 0-2M   residual (written S3 on)
    short* tgt16  = (short*)W;                      // 0-0.5M  (dead before xb written)
    float* tmp    = W + 2 * M1;                     // 2M-4M  pre-LN / split-K target
    short* mem16  = (short*)(W + 2 * M1);           // 2M-2.5M (tmp dead during C1 gemms)
    short* xb16   = (short*)(W + 4 * M1);           // 4M-5M
    float* proj   = W + 5 * M1;                     // 5M-6M
    short* qpk    = (short*)(W + 5 * M1);           // 5M-6M (proj dead after its cast)
    short* proj16 = (short*)(W + 6 * M1);           // 6M-6.5M
    float* qkvb   = W + 6 * M1 + M1 / 2;            // 6.5M-12.5M fused qkv / cross q|kv
    short* attnb16= (short*)(W + 6 * M1 + M1 / 2);  // 6.5M-7.5M (qkv dead during attn)
    short* ffh16  = (short*)(W + 7 * M1 + M1 / 2);  // 7.5M-11.5M FFN hidden bf16
    short* wslot  = (short*)(W + 12 * M1 + M1 / 2); // 12.5M-14.5M transposed weights
    short* kpk    = (short*)(W + 12 * M1 + M1 / 2); // 12.5M-13.5M (wslot dead during packs/attn)
    short* vpk    = (short*)(W + 13 * M1 + M1 / 2); // 13.5M-14.5M
    float* bcat   = W + 14 * M1 + M1 / 2;           // 14.5M+ bias concat scratch

    auto gemm = [&](const short* A, const float* Wt, const float* bias, float* C, short* C16,
                    int M, int N, int K, int act, int S) {
        transpose_bf16<<<dim3(N / 32, K / 32), dim3(256), 0, stream>>>(Wt, wslot, K, N);
        if (S > 1)
            bias_fill<<<dim3(M * N / 1024), dim3(256), 0, stream>>>(bias, C, N, M * N / 4);
        gemm_mfma<<<dim3(N / 128, M / 128, S), dim3(256), 0, stream>>>(A, wslot, bias, C, C16, M, N, K, act, S);
    };
    dim3 agrid(kL / AQ, kH, kB);
    dim3 vgrid(kL / 64, kH, kB);
    dim3 tgD(kD / 32, kP / 32);

    // ---- self attention ----
    cast_bf16<<<dim3(2048), dim3(256), 0, stream>>>(tgt, tgt16, kTok * kD / 4);
    gemm(tgt16, sa_lat_w, sa_lat_b, proj, nullptr, kTok, kP, kD, 0, 4);
    cast_bf16<<<dim3(1024), dim3(256), 0, stream>>>(proj, proj16, kTok * kP / 4);
    transpose_bf16<<<tgD, dim3(256), 0, stream>>>(sa_q_w, wslot, kP, kD);
    transpose_bf16<<<tgD, dim3(256), 0, stream>>>(sa_k_w, wslot + (size_t)kD * kP, kP, kD);
    transpose_bf16<<<tgD, dim3(256), 0, stream>>>(sa_v_w, wslot + (size_t)2 * kD * kP, kP, kD);
    concat_bias<<<dim3(12), dim3(256), 0, stream>>>(bcat, sa_q_b, sa_k_b, sa_v_b, kD);
    gemm_mfma<<<dim3(3 * kD / 128, kTok / 128, 1), dim3(256), 0, stream>>>(
        proj16, wslot, bcat, qkvb, nullptr, kTok, 3 * kD, kP, 0, 1);
    qk_pack<<<dim3(4096), dim3(256), 0, stream>>>(qkvb, self_pos, qpk, 0.125f, 3 * kD, 0);
    qk_pack<<<dim3(4096), dim3(256), 0, stream>>>(qkvb, self_pos, kpk, 1.0f, 3 * kD, kD);
    v_pack<<<vgrid, dim3(256), 0, stream>>>(qkvb, vpk, 3 * kD, 2 * kD);
    attn_mfma<<<agrid, dim3(256), 0, stream>>>(qpk, kpk, vpk, self_alibi, mask, attnb16);
    gemm(attnb16, sa_out_w, sa_out_b, tmp, nullptr, kTok, kD, kD, 0, 2);
    add_ln<<<dim3(kTok), dim3(256), 0, stream>>>(tgt, tmp, n1_g, n1_b, xb, xb16);

    // ---- cross attention ----
    cast_bf16<<<dim3(2048), dim3(256), 0, stream>>>(memory, mem16, kTok * kD / 4);
    gemm(mem16, ca_lat_w, ca_lat_b, proj, nullptr, kTok, kP, kD, 0, 4);
    cast_bf16<<<dim3(1024), dim3(256), 0, stream>>>(proj, proj16, kTok * kP / 4);
    float* qb  = qkvb;             // [2048][1024]
    float* kvb = qkvb + 2 * M1;    // [2048][2048]
    gemm(xb16, ca_q_w, ca_q_b, qb, nullptr, kTok, kD, kD, 0, 2);
    transpose_bf16<<<tgD, dim3(256), 0, stream>>>(ca_k_w, wslot, kP, kD);
    transpose_bf16<<<tgD, dim3(256), 0, stream>>>(ca_v_w, wslot + (size_t)kD * kP, kP, kD);
    concat_bias<<<dim3(8), dim3(256), 0, stream>>>(bcat, ca_k_b, ca_v_b, nullptr, kD);
    gemm_mfma<<<dim3(2 * kD / 128, kTok / 128, 1), dim3(256), 0, stream>>>(
        proj16, wslot, bcat, kvb, nullptr, kTok, 2 * kD, kP, 0, 1);
    qk_pack<<<dim3(4096), dim3(256), 0, stream>>>(qb, cross_pos, qpk, 0.125f, kD, 0);
    qk_pack<<<dim3(4096), dim3(256), 0, stream>>>(kvb, cross_pos, kpk, 1.0f, 2 * kD, 0);
    v_pack<<<vgrid, dim3(256), 0, stream>>>(kvb, vpk, 2 * kD, kD);
    attn_mfma<<<agrid, dim3(256), 0, stream>>>(qpk, kpk, vpk, cross_alibi, mask, attnb16);
    gemm(attnb16, ca_out_w, ca_out_b, tmp, nullptr, kTok, kD, kD, 0, 2);
    add_ln<<<dim3(kTok), dim3(256), 0, stream>>>(xb, tmp, n2_g, n2_b, xb, xb16);

    // ---- FFN ----
    gemm(xb16, lin1_w, lin1_b, nullptr, ffh16, kTok, kFF, kD, 1, 1);
    gemm(ffh16, lin2_w, lin2_b, tmp, nullptr, kTok, kD, kFF, 0, 4);
    ln_final<<<dim3(kTok), dim3(256), 0, stream>>>(xb, tmp, n3_g, n3_b, (float*)d_out);
}

// Round 7
// 710.214 us; speedup vs baseline: 1.0001x; 1.0001x over previous
//
#include <hip/hip_runtime.h>
#include <hip/hip_bf16.h>
#include <math.h>

typedef __hip_bfloat16 hbf16;
typedef __attribute__((ext_vector_type(8))) short bf16x8;
typedef __attribute__((ext_vector_type(4))) float f32x4;

constexpr int kD  = 1024;
constexpr int kP  = 512;
constexpr int kH  = 16;
constexpr int kFF = 4096;
constexpr int kHD = 64;
constexpr int kB  = 2;
constexpr int kL  = 1024;
constexpr int kTok = kB * kL;   // 2048

__device__ inline short f2bf(float x) { hbf16 h = __float2bfloat16(x); return *(short*)&h; }

__device__ __forceinline__ void gload16(const void* g, void* l) {
    __builtin_amdgcn_global_load_lds(
        (const __attribute__((address_space(1))) void*)g,
        (__attribute__((address_space(3))) void*)l, 16, 0, 0);
}

// ---------------- fp32 -> bf16 cast ----------------
__global__ __launch_bounds__(256) void cast_bf16(
    const float* __restrict__ in, short* __restrict__ out, int total4)
{
    int i = blockIdx.x * 256 + threadIdx.x;
    if (i >= total4) return;
    float4 v = *(const float4*)&in[(size_t)i * 4];
    *(short4*)&out[(size_t)i * 4] = make_short4(f2bf(v.x), f2bf(v.y), f2bf(v.z), f2bf(v.w));
}

// ---------------- weight transpose+convert: fp32 [K][N] -> bf16-bits [N][K] ----------------
__global__ __launch_bounds__(256) void transpose_bf16(
    const float* __restrict__ src, short* __restrict__ dst, int K, int N)
{
    __shared__ float t[32][33];
    int n0 = blockIdx.x * 32, k0 = blockIdx.y * 32;
    int tx = threadIdx.x & 31, ty = threadIdx.x >> 5;
    #pragma unroll
    for (int r = ty; r < 32; r += 8)
        t[r][tx] = src[(size_t)(k0 + r) * N + n0 + tx];
    __syncthreads();
    #pragma unroll
    for (int r = ty; r < 32; r += 8)
        dst[(size_t)(n0 + r) * K + k0 + tx] = f2bf(t[tx][r]);
}

// ---------------- bias broadcast fill: C[m][n] = bias[n] (N power of two) ----------------
__global__ __launch_bounds__(256) void bias_fill(
    const float* __restrict__ bias, float* __restrict__ C, int N, int total4)
{
    int i = blockIdx.x * 256 + threadIdx.x;
    if (i >= total4) return;
    int n = (i * 4) & (N - 1);
    *(float4*)&C[(size_t)i * 4] = *(const float4*)&bias[n];
}

// ---------------- concat up to 3 bias vectors of length n ----------------
__global__ void concat_bias(float* __restrict__ o, const float* __restrict__ a,
                            const float* __restrict__ b, const float* __restrict__ c, int n)
{
    int i = blockIdx.x * blockDim.x + threadIdx.x;
    if (i < n) o[i] = a[i];
    else if (i < 2 * n) { if (b) o[i] = b[i - n]; }
    else if (i < 3 * n) { if (c) o[i] = c[i - 2 * n]; }
}

// ---------------- MFMA GEMM: 4-deep DMA ring, counted vmcnt, raw barriers ----------------
// LDS per 128x32 tile: 8 groups of (16 rows x 32 shorts), fragment-ordered; lane l reads
// &buf[g*512 + l*8] -> 1024 contiguous B per wave read, conflict-free (verified R6: 0 conflicts).
// Pipeline: tiles t..t+3 in flight (4 DMAs/wave/tile). Steady-state wait vmcnt(12) -> only
// tile t's DMAs must have landed; loads for t+1..t+3 stay in flight ACROSS the raw barriers.
__global__ __launch_bounds__(256) void gemm_mfma(
    const short* __restrict__ A, const short* __restrict__ WT,
    const float* __restrict__ bias, float* __restrict__ C, short* __restrict__ C16,
    int M, int N, int K, int act, int ksplit)
{
    __shared__ short As[4][4096];
    __shared__ short Bs[4][4096];
    const int tid = threadIdx.x;

    // bijective XCD-aware swizzle over linearized (x,y) grid
    const int gx = gridDim.x;
    const int nwg = gx * gridDim.y;
    const int orig = blockIdx.y * gx + blockIdx.x;
    const int qq = nwg >> 3, rr = nwg & 7;
    const int xcd = orig & 7, lid = orig >> 3;
    const int swz = (xcd < rr) ? (xcd * (qq + 1) + lid)
                               : (rr * (qq + 1) + (xcd - rr) * qq + lid);
    const int m0 = (swz / gx) * 128, n0 = (swz % gx) * 128;

    const int ks = K / ksplit;
    const int kbeg = blockIdx.z * ks;
    const int nt = ks / 32;
    const int wave = tid >> 6, lane = tid & 63;
    const int l15 = lane & 15, quad = lane >> 4;
    const int wm = (wave & 1) * 64, wn = (wave >> 1) * 64;

    // staging source coords (fragment-ordered): row-in-group (lane&15), 8-short col ((lane>>4)*8)
    const int sgr = lane & 15;
    const int sgq = (lane >> 4) * 8;
    const size_t arow0 = (size_t)(m0 + wave * 32 + sgr) * K + sgq + kbeg;
    const size_t arow1 = arow0 + (size_t)16 * K;
    const size_t brow0 = (size_t)(n0 + wave * 32 + sgr) * K + sgq + kbeg;
    const size_t brow1 = brow0 + (size_t)16 * K;

    f32x4 acc[4][4];
    #pragma unroll
    for (int i = 0; i < 4; ++i)
        #pragma unroll
        for (int j = 0; j < 4; ++j)
            acc[i][j] = (f32x4){0.f, 0.f, 0.f, 0.f};

    auto issue = [&](int t) {
        int bi = t & 3;
        int koff = t * 32;
        gload16(&A [arow0 + koff], &As[bi][(wave * 2) * 512]);
        gload16(&A [arow1 + koff], &As[bi][(wave * 2 + 1) * 512]);
        gload16(&WT[brow0 + koff], &Bs[bi][(wave * 2) * 512]);
        gload16(&WT[brow1 + koff], &Bs[bi][(wave * 2 + 1) * 512]);
    };

    // prologue: fill the ring (nt >= 8 for every call site)
    issue(0); issue(1); issue(2); issue(3);

    const int ga = (wave & 1) * 4, gb = (wave >> 1) * 4;
    for (int t = 0; t < nt; ++t) {
        int ahead = nt - 1 - t; if (ahead > 3) ahead = 3;
        // wait until this wave's tile-t DMAs have landed (4*ahead still outstanding)
        if (ahead == 3)      asm volatile("s_waitcnt vmcnt(12)" ::: "memory");
        else if (ahead == 2) asm volatile("s_waitcnt vmcnt(8)"  ::: "memory");
        else if (ahead == 1) asm volatile("s_waitcnt vmcnt(4)"  ::: "memory");
        else                 asm volatile("s_waitcnt vmcnt(0)"  ::: "memory");
        __builtin_amdgcn_sched_barrier(0);
        __builtin_amdgcn_s_barrier();      // all waves' tile-t stages visible

        int bi = t & 3;
        bf16x8 af[4], bfr[4];
        #pragma unroll
        for (int i = 0; i < 4; ++i)
            af[i] = *(bf16x8*)&As[bi][(ga + i) * 512 + lane * 8];
        #pragma unroll
        for (int j = 0; j < 4; ++j)
            bfr[j] = *(bf16x8*)&Bs[bi][(gb + j) * 512 + lane * 8];
        #pragma unroll
        for (int i = 0; i < 4; ++i)
            #pragma unroll
            for (int j = 0; j < 4; ++j)
                acc[i][j] = __builtin_amdgcn_mfma_f32_16x16x32_bf16(af[i], bfr[j], acc[i][j], 0, 0, 0);

        asm volatile("s_waitcnt lgkmcnt(0)" ::: "memory");   // all my LDS reads of buf[bi] done
        __builtin_amdgcn_sched_barrier(0);
        __builtin_amdgcn_s_barrier();      // everyone done reading buf[bi]
        if (t + 4 < nt) issue(t + 4);      // safe to overwrite buf[bi]
    }

    #pragma unroll
    for (int j = 0; j < 4; ++j) {
        int n = n0 + wn + j * 16 + l15;
        if (ksplit == 1) {
            float bv = bias[n];
            #pragma unroll
            for (int i = 0; i < 4; ++i) {
                int mb = m0 + wm + i * 16 + quad * 4;
                #pragma unroll
                for (int r = 0; r < 4; ++r) {
                    float v = acc[i][j][r] + bv;
                    if (act) v = v * 0.5f * (1.0f + erff(v * 0.70710678118654752f));
                    if (C)   C[(size_t)(mb + r) * N + n] = v;
                    if (C16) C16[(size_t)(mb + r) * N + n] = f2bf(v);
                }
            }
        } else {
            #pragma unroll
            for (int i = 0; i < 4; ++i) {
                int mb = m0 + wm + i * 16 + quad * 4;
                #pragma unroll
                for (int r = 0; r < 4; ++r)
                    atomicAdd(&C[(size_t)(mb + r) * N + n], acc[i][j][r]);
            }
        }
    }
}

// ---------------- qk_pack: RoPE + optional scale + bf16 cast, [Tok,ldx] -> [b,h,l,64] ----------------
__global__ void qk_pack(const float* __restrict__ x, const float* __restrict__ pos,
                        short* __restrict__ outp, float scale, int ldx, int off)
{
    int idx = blockIdx.x * blockDim.x + threadIdx.x;
    if (idx >= kTok * kH * 32) return;
    int d = idx & 31;
    int h = (idx >> 5) & (kH - 1);
    int row = idx >> 9;
    int l = row & (kL - 1);
    int b = row >> 10;
    float a1 = pos[l * kHD + d];
    float a2 = pos[l * kHD + d + 32];
    size_t base = (size_t)row * ldx + off + h * kHD;
    float x1 = x[base + d], x2 = x[base + d + 32];
    float r1 = (x1 * cosf(a1) - x2 * sinf(a1)) * scale;
    float r2 = (x2 * cosf(a2) + x1 * sinf(a2)) * scale;
    size_t ob = ((size_t)(b * kH + h) * kL + l) * 64;
    outp[ob + d]      = f2bf(r1);
    outp[ob + d + 32] = f2bf(r2);
}

// ---------------- v_pack: transpose [Tok,ldx] fp32 -> [b,h,hd,l] bf16 ----------------
__global__ __launch_bounds__(256) void v_pack(const float* __restrict__ v, short* __restrict__ outp,
                                              int ldx, int off)
{
    int l0 = blockIdx.x * 64, h = blockIdx.y, b = blockIdx.z;
    __shared__ float t[64][65];
    int tid = threadIdx.x;
    #pragma unroll
    for (int e = 0; e < 4; ++e) {
        int idx = tid + e * 256;
        int r = idx >> 4, c4 = (idx & 15) * 4;
        const float4 vv = *(const float4*)&v[(size_t)(b * kL + l0 + r) * ldx + off + h * kHD + c4];
        t[r][c4] = vv.x; t[r][c4 + 1] = vv.y; t[r][c4 + 2] = vv.z; t[r][c4 + 3] = vv.w;
    }
    __syncthreads();
    int hd = tid >> 2, seg = (tid & 3) * 16;
    size_t ob = ((size_t)(b * kH + h) * 64 + hd) * kL + l0 + seg;
    short tmp[16];
    #pragma unroll
    for (int i = 0; i < 16; ++i) tmp[i] = f2bf(t[seg + i][hd]);
    #pragma unroll
    for (int i = 0; i < 16; i += 4)
        *(short4*)&outp[ob + i] = make_short4(tmp[i], tmp[i + 1], tmp[i + 2], tmp[i + 3]);
}

// ---------------- MFMA flash attention (fragment-ordered LDS, staged alibi; bf16 out) ----------------
constexpr int AQ = 64, AK = 64;
__global__ __launch_bounds__(256, 2) void attn_mfma(
    const short* __restrict__ qpk, const short* __restrict__ kpk,
    const short* __restrict__ vpk, const float* __restrict__ alibi,
    const int* __restrict__ mask, short* __restrict__ out)
{
    const int q0 = blockIdx.x * AQ, h = blockIdx.y, b = blockIdx.z;
    const int tid = threadIdx.x, wave = tid >> 6, lane = tid & 63;
    const int l15 = lane & 15, quad = lane >> 4;
    __shared__ short Qf[4096];
    __shared__ short Kf[4096];
    __shared__ short Vf[4096];
    __shared__ float ALPS[4 * 1088];

    const short* qbase = qpk + ((size_t)(b * kH + h) * kL) * 64;
    const short* kbase = kpk + ((size_t)(b * kH + h) * kL) * 64;
    const short* vbase = vpk + ((size_t)(b * kH + h) * 64) * kL;
    const float* abase = alibi + ((size_t)h * kL + q0) * kL;
    const int*   mbase = mask + b * kL;

    const int sr = tid >> 3, sc8 = (tid & 7) * 8;
    const int sQuad = (sc8 >> 3) & 3, sS = sc8 >> 5;
    const int ar = tid >> 4, ac4 = (tid & 15) * 4;

    #pragma unroll
    for (int e = 0; e < 2; ++e) {
        int r = sr + e * 32;
        int slot = ((r >> 4) * 2 + sS) * 512 + (r & 15) * 32 + sQuad * 8;
        *(bf16x8*)&Qf[slot] = *(const bf16x8*)&qbase[(size_t)(q0 + r) * 64 + sc8];
    }

    bf16x8 rk[2], rv[2];
    float4 ral[4];
    int4 rmk;
    auto load_tile = [&](int k0) {
        #pragma unroll
        for (int e = 0; e < 2; ++e) {
            int r = sr + e * 32;
            rk[e] = *(const bf16x8*)&kbase[(size_t)(k0 + r) * 64 + sc8];
            rv[e] = *(const bf16x8*)&vbase[(size_t)r * kL + k0 + sc8];
        }
        #pragma unroll
        for (int e = 0; e < 4; ++e)
            ral[e] = *(const float4*)&abase[(size_t)(ar + e * 16) * kL + k0 + ac4];
        rmk = *(const int4*)&mbase[k0 + ac4];
    };
    auto store_tile = [&]() {
        #pragma unroll
        for (int e = 0; e < 2; ++e) {
            int r = sr + e * 32;
            int slot = ((r >> 4) * 2 + sS) * 512 + (r & 15) * 32 + sQuad * 8;
            *(bf16x8*)&Kf[slot] = rk[e];
            *(bf16x8*)&Vf[slot] = rv[e];
        }
        #pragma unroll
        for (int e = 0; e < 4; ++e) {
            float4 a = ral[e];
            a.x = rmk.x ? -1e30f : a.x;
            a.y = rmk.y ? -1e30f : a.y;
            a.z = rmk.z ? -1e30f : a.z;
            a.w = rmk.w ? -1e30f : a.w;
            *(float4*)&ALPS[(ar + e * 16) * 68 + ac4] = a;
        }
    };

    float mst[4], lst[4];
    #pragma unroll
    for (int r = 0; r < 4; ++r) { mst[r] = -3e38f; lst[r] = 0.f; }
    f32x4 oacc[4];
    #pragma unroll
    for (int j = 0; j < 4; ++j) oacc[j] = (f32x4){0.f, 0.f, 0.f, 0.f};

    load_tile(0);
    __syncthreads();

    bf16x8 aq[2];
    #pragma unroll
    for (int s = 0; s < 2; ++s)
        aq[s] = *(bf16x8*)&Qf[(wave * 2 + s) * 512 + l15 * 32 + quad * 8];

    for (int t = 0; t < kL / AK; ++t) {
        store_tile();
        __syncthreads();
        if (t + 1 < kL / AK) load_tile((t + 1) * AK);

        f32x4 sacc[4];
        #pragma unroll
        for (int nt = 0; nt < 4; ++nt) sacc[nt] = (f32x4){0.f, 0.f, 0.f, 0.f};
        #pragma unroll
        for (int nt = 0; nt < 4; ++nt)
            #pragma unroll
            for (int s = 0; s < 2; ++s) {
                bf16x8 bk = *(bf16x8*)&Kf[(nt * 2 + s) * 512 + l15 * 32 + quad * 8];
                sacc[nt] = __builtin_amdgcn_mfma_f32_16x16x32_bf16(aq[s], bk, sacc[nt], 0, 0, 0);
            }

        float sv[4][4];
        float mx[4] = {-3e38f, -3e38f, -3e38f, -3e38f};
        #pragma unroll
        for (int nt = 0; nt < 4; ++nt)
            #pragma unroll
            for (int r = 0; r < 4; ++r) {
                float al = ALPS[(wave * 16 + quad * 4 + r) * 68 + nt * 16 + l15];
                float s = sacc[nt][r] + al;
                sv[nt][r] = s;
                mx[r] = fmaxf(mx[r], s);
            }
        #pragma unroll
        for (int m = 1; m <= 8; m <<= 1)
            #pragma unroll
            for (int r = 0; r < 4; ++r)
                mx[r] = fmaxf(mx[r], __shfl_xor(mx[r], m));
        float alpha[4], lsum[4];
        #pragma unroll
        for (int r = 0; r < 4; ++r) {
            float mn = fmaxf(mst[r], mx[r]);
            alpha[r] = __expf(mst[r] - mn);
            mst[r] = mn;
            lsum[r] = 0.f;
        }
        #pragma unroll
        for (int nt = 0; nt < 4; ++nt)
            #pragma unroll
            for (int r = 0; r < 4; ++r) {
                float p = __expf(sv[nt][r] - mst[r]);
                sv[nt][r] = p;
                lsum[r] += p;
            }
        #pragma unroll
        for (int m = 1; m <= 8; m <<= 1)
            #pragma unroll
            for (int r = 0; r < 4; ++r)
                lsum[r] += __shfl_xor(lsum[r], m);
        #pragma unroll
        for (int r = 0; r < 4; ++r) lst[r] = lst[r] * alpha[r] + lsum[r];

        #pragma unroll
        for (int nt = 0; nt < 4; ++nt)
            #pragma unroll
            for (int r = 0; r < 4; ++r)
                ALPS[wave * 1088 + (quad * 4 + r) * 67 + nt * 16 + l15] = sv[nt][r];
        #pragma unroll
        for (int j = 0; j < 4; ++j)
            #pragma unroll
            for (int r = 0; r < 4; ++r)
                oacc[j][r] *= alpha[r];

        #pragma unroll
        for (int s = 0; s < 2; ++s) {
            int pb = wave * 1088 + l15 * 67 + s * 32 + quad * 8;
            bf16x8 ap;
            #pragma unroll
            for (int e = 0; e < 8; ++e) ap[e] = f2bf(ALPS[pb + e]);
            #pragma unroll
            for (int j = 0; j < 4; ++j) {
                bf16x8 bv = *(bf16x8*)&Vf[(j * 2 + s) * 512 + l15 * 32 + quad * 8];
                oacc[j] = __builtin_amdgcn_mfma_f32_16x16x32_bf16(ap, bv, oacc[j], 0, 0, 0);
            }
        }
        __syncthreads();
    }

    #pragma unroll
    for (int j = 0; j < 4; ++j)
        #pragma unroll
        for (int r = 0; r < 4; ++r) {
            int qrow = q0 + wave * 16 + quad * 4 + r;
            out[(size_t)(b * kL + qrow) * kD + h * kHD + j * 16 + l15] = f2bf(oacc[j][r] / lst[r]);
        }
}

// ---------------- out = res + LayerNorm(z); also bf16 copy ----------------
__global__ __launch_bounds__(256) void add_ln(
    const float* __restrict__ res, const float* __restrict__ z,
    const float* __restrict__ g, const float* __restrict__ bi,
    float* __restrict__ out, short* __restrict__ out16)
{
    int row = blockIdx.x, tid = threadIdx.x;
    __shared__ float red[256], red2[256];
    const float* zr = z + (size_t)row * kD;
    float s = 0.f, sq = 0.f;
    for (int i = tid; i < kD; i += 256) { float vv = zr[i]; s += vv; sq += vv * vv; }
    red[tid] = s; red2[tid] = sq; __syncthreads();
    for (int st = 128; st > 0; st >>= 1) {
        if (tid < st) { red[tid] += red[tid + st]; red2[tid] += red2[tid + st]; }
        __syncthreads();
    }
    float mean = red[0] / kD;
    float var = red2[0] / kD - mean * mean;
    float rstd = rsqrtf(var + 1e-5f);
    for (int i = tid; i < kD; i += 256) {
        float vv = (zr[i] - mean) * rstd * g[i] + bi[i];
        float o = res[(size_t)row * kD + i] + vv;
        out[(size_t)row * kD + i] = o;
        out16[(size_t)row * kD + i] = f2bf(o);
    }
}

// ---------------- out = LayerNorm(res + f) ----------------
__global__ __launch_bounds__(256) void ln_final(
    const float* __restrict__ res, const float* __restrict__ f,
    const float* __restrict__ g, const float* __restrict__ bi,
    float* __restrict__ out)
{
    int row = blockIdx.x, tid = threadIdx.x;
    __shared__ float tt[kD];
    __shared__ float red[256], red2[256];
    float s = 0.f, sq = 0.f;
    for (int i = tid; i < kD; i += 256) {
        float vv = res[(size_t)row * kD + i] + f[(size_t)row * kD + i];
        tt[i] = vv; s += vv; sq += vv * vv;
    }
    red[tid] = s; red2[tid] = sq; __syncthreads();
    for (int st = 128; st > 0; st >>= 1) {
        if (tid < st) { red[tid] += red[tid + st]; red2[tid] += red2[tid + st]; }
        __syncthreads();
    }
    float mean = red[0] / kD;
    float var = red2[0] / kD - mean * mean;
    float rstd = rsqrtf(var + 1e-5f);
    for (int i = tid; i < kD; i += 256)
        out[(size_t)row * kD + i] = (tt[i] - mean) * rstd * g[i] + bi[i];
}

extern "C" void kernel_launch(void* const* d_in, const int* in_sizes, int n_in,
                              void* d_out, int out_size, void* d_ws, size_t ws_size,
                              hipStream_t stream)
{
    const float* memory      = (const float*)d_in[0];
    const float* tgt         = (const float*)d_in[1];
    const float* self_alibi  = (const float*)d_in[2];
    const float* self_pos    = (const float*)d_in[3];
    const float* cross_alibi = (const float*)d_in[4];
    const float* cross_pos   = (const float*)d_in[5];
    const int*   mask        = (const int*)d_in[6];
    const float* sa_lat_w = (const float*)d_in[7];   const float* sa_lat_b = (const float*)d_in[8];
    const float* sa_q_w   = (const float*)d_in[9];   const float* sa_q_b   = (const float*)d_in[10];
    const float* sa_k_w   = (const float*)d_in[11];  const float* sa_k_b   = (const float*)d_in[12];
    const float* sa_v_w   = (const float*)d_in[13];  const float* sa_v_b   = (const float*)d_in[14];
    const float* sa_out_w = (const float*)d_in[15];  const float* sa_out_b = (const float*)d_in[16];
    const float* ca_lat_w = (const float*)d_in[17];  const float* ca_lat_b = (const float*)d_in[18];
    const float* ca_q_w   = (const float*)d_in[19];  const float* ca_q_b   = (const float*)d_in[20];
    const float* ca_k_w   = (const float*)d_in[21];  const float* ca_k_b   = (const float*)d_in[22];
    const float* ca_v_w   = (const float*)d_in[23];  const float* ca_v_b   = (const float*)d_in[24];
    const float* ca_out_w = (const float*)d_in[25];  const float* ca_out_b = (const float*)d_in[26];
    const float* lin1_w   = (const float*)d_in[27];  const float* lin1_b   = (const float*)d_in[28];
    const float* lin2_w   = (const float*)d_in[29];  const float* lin2_b   = (const float*)d_in[30];
    const float* n1_g = (const float*)d_in[31];  const float* n1_b = (const float*)d_in[32];
    const float* n2_g = (const float*)d_in[33];  const float* n2_b = (const float*)d_in[34];
    const float* n3_g = (const float*)d_in[35];  const float* n3_b = (const float*)d_in[36];

    // workspace map (floats; M1 = 1M floats = 4 MB). Total 15M floats = 60 MB.
    const size_t M1 = 1u << 20;
    float* W      = (float*)d_ws;
    float* xb     = W;                              // 0-2M   residual (written S3 on)
    short* tgt16  = (short*)W;                      // 0-0.5M  (dead before xb written)
    float* tmp    = W + 2 * M1;                     // 2M-4M  pre-LN / split-K target
    short* mem16  = (short*)(W + 2 * M1);           // 2M-2.5M (tmp dead during C1 gemms)
    short* xb16   = (short*)(W + 4 * M1);           // 4M-5M
    float* proj   = W + 5 * M1;                     // 5M-6M
    short* qpk    = (short*)(W + 5 * M1);           // 5M-6M (proj dead after its cast)
    short* proj16 = (short*)(W + 6 * M1);           // 6M-6.5M
    float* qkvb   = W + 6 * M1 + M1 / 2;            // 6.5M-12.5M fused qkv / cross q|kv
    short* attnb16= (short*)(W + 6 * M1 + M1 / 2);  // 6.5M-7.5M (qkv dead during attn)
    short* ffh16  = (short*)(W + 7 * M1 + M1 / 2);  // 7.5M-11.5M FFN hidden bf16
    short* wslot  = (short*)(W + 12 * M1 + M1 / 2); // 12.5M-14.5M transposed weights
    short* kpk    = (short*)(W + 12 * M1 + M1 / 2); // 12.5M-13.5M (wslot dead during packs/attn)
    short* vpk    = (short*)(W + 13 * M1 + M1 / 2); // 13.5M-14.5M
    float* bcat   = W + 14 * M1 + M1 / 2;           // 14.5M+ bias concat scratch

    auto gemm = [&](const short* A, const float* Wt, const float* bias, float* C, short* C16,
                    int M, int N, int K, int act, int S) {
        transpose_bf16<<<dim3(N / 32, K / 32), dim3(256), 0, stream>>>(Wt, wslot, K, N);
        if (S > 1)
            bias_fill<<<dim3(M * N / 1024), dim3(256), 0, stream>>>(bias, C, N, M * N / 4);
        gemm_mfma<<<dim3(N / 128, M / 128, S), dim3(256), 0, stream>>>(A, wslot, bias, C, C16, M, N, K, act, S);
    };
    dim3 agrid(kL / AQ, kH, kB);
    dim3 vgrid(kL / 64, kH, kB);
    dim3 tgD(kD / 32, kP / 32);

    // ---- self attention ----
    cast_bf16<<<dim3(2048), dim3(256), 0, stream>>>(tgt, tgt16, kTok * kD / 4);
    gemm(tgt16, sa_lat_w, sa_lat_b, proj, nullptr, kTok, kP, kD, 0, 4);
    cast_bf16<<<dim3(1024), dim3(256), 0, stream>>>(proj, proj16, kTok * kP / 4);
    transpose_bf16<<<tgD, dim3(256), 0, stream>>>(sa_q_w, wslot, kP, kD);
    transpose_bf16<<<tgD, dim3(256), 0, stream>>>(sa_k_w, wslot + (size_t)kD * kP, kP, kD);
    transpose_bf16<<<tgD, dim3(256), 0, stream>>>(sa_v_w, wslot + (size_t)2 * kD * kP, kP, kD);
    concat_bias<<<dim3(12), dim3(256), 0, stream>>>(bcat, sa_q_b, sa_k_b, sa_v_b, kD);
    gemm_mfma<<<dim3(3 * kD / 128, kTok / 128, 1), dim3(256), 0, stream>>>(
        proj16, wslot, bcat, qkvb, nullptr, kTok, 3 * kD, kP, 0, 1);
    qk_pack<<<dim3(4096), dim3(256), 0, stream>>>(qkvb, self_pos, qpk, 0.125f, 3 * kD, 0);
    qk_pack<<<dim3(4096), dim3(256), 0, stream>>>(qkvb, self_pos, kpk, 1.0f, 3 * kD, kD);
    v_pack<<<vgrid, dim3(256), 0, stream>>>(qkvb, vpk, 3 * kD, 2 * kD);
    attn_mfma<<<agrid, dim3(256), 0, stream>>>(qpk, kpk, vpk, self_alibi, mask, attnb16);
    gemm(attnb16, sa_out_w, sa_out_b, tmp, nullptr, kTok, kD, kD, 0, 2);
    add_ln<<<dim3(kTok), dim3(256), 0, stream>>>(tgt, tmp, n1_g, n1_b, xb, xb16);

    // ---- cross attention ----
    cast_bf16<<<dim3(2048), dim3(256), 0, stream>>>(memory, mem16, kTok * kD / 4);
    gemm(mem16, ca_lat_w, ca_lat_b, proj, nullptr, kTok, kP, kD, 0, 4);
    cast_bf16<<<dim3(1024), dim3(256), 0, stream>>>(proj, proj16, kTok * kP / 4);
    float* qb  = qkvb;             // [2048][1024]
    float* kvb = qkvb + 2 * M1;    // [2048][2048]
    gemm(xb16, ca_q_w, ca_q_b, qb, nullptr, kTok, kD, kD, 0, 2);
    transpose_bf16<<<tgD, dim3(256), 0, stream>>>(ca_k_w, wslot, kP, kD);
    transpose_bf16<<<tgD, dim3(256), 0, stream>>>(ca_v_w, wslot + (size_t)kD * kP, kP, kD);
    concat_bias<<<dim3(8), dim3(256), 0, stream>>>(bcat, ca_k_b, ca_v_b, nullptr, kD);
    gemm_mfma<<<dim3(2 * kD / 128, kTok / 128, 1), dim3(256), 0, stream>>>(
        proj16, wslot, bcat, kvb, nullptr, kTok, 2 * kD, kP, 0, 1);
    qk_pack<<<dim3(4096), dim3(256), 0, stream>>>(qb, cross_pos, qpk, 0.125f, kD, 0);
    qk_pack<<<dim3(4096), dim3(256), 0, stream>>>(kvb, cross_pos, kpk, 1.0f, 2 * kD, 0);
    v_pack<<<vgrid, dim3(256), 0, stream>>>(kvb, vpk, 2 * kD, kD);
    attn_mfma<<<agrid, dim3(256), 0, stream>>>(qpk, kpk, vpk, cross_alibi, mask, attnb16);
    gemm(attnb16, ca_out_w, ca_out_b, tmp, nullptr, kTok, kD, kD, 0, 2);
    add_ln<<<dim3(kTok), dim3(256), 0, stream>>>(xb, tmp, n2_g, n2_b, xb, xb16);

    // ---- FFN ----
    gemm(xb16, lin1_w, lin1_b, nullptr, ffh16, kTok, kFF, kD, 1, 1);
    gemm(ffh16, lin2_w, lin2_b, tmp, nullptr, kTok, kD, kFF, 0, 4);
    ln_final<<<dim3(kTok), dim3(256), 0, stream>>>(xb, tmp, n3_g, n3_b, (float*)d_out);
}

// Round 8
// 661.068 us; speedup vs baseline: 1.0744x; 1.0743x over previous
//
#include <hip/hip_runtime.h>
#include <hip/hip_bf16.h>
#include <math.h>

typedef __hip_bfloat16 hbf16;
typedef __attribute__((ext_vector_type(8))) short bf16x8;
typedef __attribute__((ext_vector_type(4))) float f32x4;

constexpr int kD  = 1024;
constexpr int kP  = 512;
constexpr int kH  = 16;
constexpr int kFF = 4096;
constexpr int kHD = 64;
constexpr int kB  = 2;
constexpr int kL  = 1024;
constexpr int kTok = kB * kL;   // 2048

__device__ inline short f2bf(float x) { hbf16 h = __float2bfloat16(x); return *(short*)&h; }

__device__ __forceinline__ void gload16(const void* g, void* l) {
    __builtin_amdgcn_global_load_lds(
        (const __attribute__((address_space(1))) void*)g,
        (__attribute__((address_space(3))) void*)l, 16, 0, 0);
}

// ---------------- fp32 -> bf16 cast ----------------
__global__ __launch_bounds__(256) void cast_bf16(
    const float* __restrict__ in, short* __restrict__ out, int total4)
{
    int i = blockIdx.x * 256 + threadIdx.x;
    if (i >= total4) return;
    float4 v = *(const float4*)&in[(size_t)i * 4];
    *(short4*)&out[(size_t)i * 4] = make_short4(f2bf(v.x), f2bf(v.y), f2bf(v.z), f2bf(v.w));
}

// ---------------- weight transpose+convert: fp32 [K][N] -> bf16-bits [N][K] ----------------
__global__ __launch_bounds__(256) void transpose_bf16(
    const float* __restrict__ src, short* __restrict__ dst, int K, int N)
{
    __shared__ float t[32][33];
    int n0 = blockIdx.x * 32, k0 = blockIdx.y * 32;
    int tx = threadIdx.x & 31, ty = threadIdx.x >> 5;
    #pragma unroll
    for (int r = ty; r < 32; r += 8)
        t[r][tx] = src[(size_t)(k0 + r) * N + n0 + tx];
    __syncthreads();
    #pragma unroll
    for (int r = ty; r < 32; r += 8)
        dst[(size_t)(n0 + r) * K + k0 + tx] = f2bf(t[tx][r]);
}

// ---------------- concat up to 3 bias vectors of length n ----------------
__global__ void concat_bias(float* __restrict__ o, const float* __restrict__ a,
                            const float* __restrict__ b, const float* __restrict__ c, int n)
{
    int i = blockIdx.x * blockDim.x + threadIdx.x;
    if (i < n) o[i] = a[i];
    else if (i < 2 * n) { if (b) o[i] = b[i - n]; }
    else if (i < 3 * n) { if (c) o[i] = c[i - 2 * n]; }
}

// ---------------- sum 4 split-K partials + bias -> bf16 ----------------
__global__ __launch_bounds__(256) void reduce4_cast(
    const float* __restrict__ p, size_t stride, const float* __restrict__ bias,
    short* __restrict__ out16, int total4, int N)
{
    int i = blockIdx.x * 256 + threadIdx.x;
    if (i >= total4) return;
    size_t off = (size_t)i * 4;
    int n = (int)(off & (size_t)(N - 1));
    float4 a0 = *(const float4*)&p[off];
    float4 a1 = *(const float4*)&p[off + stride];
    float4 a2 = *(const float4*)&p[off + 2 * stride];
    float4 a3 = *(const float4*)&p[off + 3 * stride];
    float4 b  = *(const float4*)&bias[n];
    *(short4*)&out16[off] = make_short4(
        f2bf(a0.x + a1.x + a2.x + a3.x + b.x),
        f2bf(a0.y + a1.y + a2.y + a3.y + b.y),
        f2bf(a0.z + a1.z + a2.z + a3.z + b.z),
        f2bf(a0.w + a1.w + a2.w + a3.w + b.w));
}

// ---------------- out = res + LayerNorm(p0+p1+bias); also bf16 copy ----------------
__global__ __launch_bounds__(256) void add_ln2(
    const float* __restrict__ res, const float* __restrict__ p, size_t stride,
    const float* __restrict__ bias, const float* __restrict__ g, const float* __restrict__ bi,
    float* __restrict__ out, short* __restrict__ out16)
{
    int row = blockIdx.x, tid = threadIdx.x;
    __shared__ float tt[kD];
    __shared__ float red[256], red2[256];
    const float* zr = p + (size_t)row * kD;
    float s = 0.f, sq = 0.f;
    for (int i = tid; i < kD; i += 256) {
        float vv = zr[i] + zr[i + stride] + bias[i];
        tt[i] = vv; s += vv; sq += vv * vv;
    }
    red[tid] = s; red2[tid] = sq; __syncthreads();
    for (int st = 128; st > 0; st >>= 1) {
        if (tid < st) { red[tid] += red[tid + st]; red2[tid] += red2[tid + st]; }
        __syncthreads();
    }
    float mean = red[0] / kD;
    float var = red2[0] / kD - mean * mean;
    float rstd = rsqrtf(var + 1e-5f);
    for (int i = tid; i < kD; i += 256) {
        float vv = (tt[i] - mean) * rstd * g[i] + bi[i];
        float o = res[(size_t)row * kD + i] + vv;
        out[(size_t)row * kD + i] = o;
        out16[(size_t)row * kD + i] = f2bf(o);
    }
}

// ---------------- out = LayerNorm(res + p0+p1+bias) ----------------
__global__ __launch_bounds__(256) void ln_final2(
    const float* __restrict__ res, const float* __restrict__ p, size_t stride,
    const float* __restrict__ bias, const float* __restrict__ g, const float* __restrict__ bi,
    float* __restrict__ out)
{
    int row = blockIdx.x, tid = threadIdx.x;
    __shared__ float tt[kD];
    __shared__ float red[256], red2[256];
    const float* zr = p + (size_t)row * kD;
    float s = 0.f, sq = 0.f;
    for (int i = tid; i < kD; i += 256) {
        float vv = res[(size_t)row * kD + i] + zr[i] + zr[i + stride] + bias[i];
        tt[i] = vv; s += vv; sq += vv * vv;
    }
    red[tid] = s; red2[tid] = sq; __syncthreads();
    for (int st = 128; st > 0; st >>= 1) {
        if (tid < st) { red[tid] += red[tid + st]; red2[tid] += red2[tid + st]; }
        __syncthreads();
    }
    float mean = red[0] / kD;
    float var = red2[0] / kD - mean * mean;
    float rstd = rsqrtf(var + 1e-5f);
    for (int i = tid; i < kD; i += 256)
        out[(size_t)row * kD + i] = (tt[i] - mean) * rstd * g[i] + bi[i];
}

// ---------------- MFMA GEMM: 4-deep DMA ring, counted vmcnt, raw barriers ----------------
// LDS per 128x32 tile: 8 groups of (16 rows x 32 shorts), fragment-ordered; conflict-free.
// Pipeline: tiles t..t+3 in flight (4 DMAs/wave/tile); never drain vmcnt to 0 mid-loop.
// ksplit==1: bias (+ gelu) fused; fp32 C and/or bf16 C16 outputs.
// ksplit>1 : plain fp32 partial stores to C + z*M*N (NO atomics; bias added by reducer).
__global__ __launch_bounds__(256) void gemm_mfma(
    const short* __restrict__ A, const short* __restrict__ WT,
    const float* __restrict__ bias, float* __restrict__ C, short* __restrict__ C16,
    int M, int N, int K, int act, int ksplit)
{
    __shared__ short As[4][4096];
    __shared__ short Bs[4][4096];
    const int tid = threadIdx.x;

    // bijective XCD-aware swizzle over linearized (x,y) grid
    const int gx = gridDim.x;
    const int nwg = gx * gridDim.y;
    const int orig = blockIdx.y * gx + blockIdx.x;
    const int qq = nwg >> 3, rr = nwg & 7;
    const int xcd = orig & 7, lid = orig >> 3;
    const int swz = (xcd < rr) ? (xcd * (qq + 1) + lid)
                               : (rr * (qq + 1) + (xcd - rr) * qq + lid);
    const int m0 = (swz / gx) * 128, n0 = (swz % gx) * 128;

    const int ks = K / ksplit;
    const int kbeg = blockIdx.z * ks;
    const int nt = ks / 32;
    const int wave = tid >> 6, lane = tid & 63;
    const int l15 = lane & 15, quad = lane >> 4;
    const int wm = (wave & 1) * 64, wn = (wave >> 1) * 64;

    const int sgr = lane & 15;
    const int sgq = (lane >> 4) * 8;
    const size_t arow0 = (size_t)(m0 + wave * 32 + sgr) * K + sgq + kbeg;
    const size_t arow1 = arow0 + (size_t)16 * K;
    const size_t brow0 = (size_t)(n0 + wave * 32 + sgr) * K + sgq + kbeg;
    const size_t brow1 = brow0 + (size_t)16 * K;

    f32x4 acc[4][4];
    #pragma unroll
    for (int i = 0; i < 4; ++i)
        #pragma unroll
        for (int j = 0; j < 4; ++j)
            acc[i][j] = (f32x4){0.f, 0.f, 0.f, 0.f};

    auto issue = [&](int t) {
        int bi = t & 3;
        int koff = t * 32;
        gload16(&A [arow0 + koff], &As[bi][(wave * 2) * 512]);
        gload16(&A [arow1 + koff], &As[bi][(wave * 2 + 1) * 512]);
        gload16(&WT[brow0 + koff], &Bs[bi][(wave * 2) * 512]);
        gload16(&WT[brow1 + koff], &Bs[bi][(wave * 2 + 1) * 512]);
    };

    issue(0); issue(1); issue(2); issue(3);

    const int ga = (wave & 1) * 4, gb = (wave >> 1) * 4;
    for (int t = 0; t < nt; ++t) {
        int ahead = nt - 1 - t; if (ahead > 3) ahead = 3;
        if (ahead == 3)      asm volatile("s_waitcnt vmcnt(12)" ::: "memory");
        else if (ahead == 2) asm volatile("s_waitcnt vmcnt(8)"  ::: "memory");
        else if (ahead == 1) asm volatile("s_waitcnt vmcnt(4)"  ::: "memory");
        else                 asm volatile("s_waitcnt vmcnt(0)"  ::: "memory");
        __builtin_amdgcn_sched_barrier(0);
        __builtin_amdgcn_s_barrier();

        int bi = t & 3;
        bf16x8 af[4], bfr[4];
        #pragma unroll
        for (int i = 0; i < 4; ++i)
            af[i] = *(bf16x8*)&As[bi][(ga + i) * 512 + lane * 8];
        #pragma unroll
        for (int j = 0; j < 4; ++j)
            bfr[j] = *(bf16x8*)&Bs[bi][(gb + j) * 512 + lane * 8];
        #pragma unroll
        for (int i = 0; i < 4; ++i)
            #pragma unroll
            for (int j = 0; j < 4; ++j)
                acc[i][j] = __builtin_amdgcn_mfma_f32_16x16x32_bf16(af[i], bfr[j], acc[i][j], 0, 0, 0);

        asm volatile("s_waitcnt lgkmcnt(0)" ::: "memory");
        __builtin_amdgcn_sched_barrier(0);
        __builtin_amdgcn_s_barrier();
        if (t + 4 < nt) issue(t + 4);
    }

    if (ksplit == 1) {
        #pragma unroll
        for (int j = 0; j < 4; ++j) {
            int n = n0 + wn + j * 16 + l15;
            float bv = bias[n];
            #pragma unroll
            for (int i = 0; i < 4; ++i) {
                int mb = m0 + wm + i * 16 + quad * 4;
                #pragma unroll
                for (int r = 0; r < 4; ++r) {
                    float v = acc[i][j][r] + bv;
                    if (act) v = v * 0.5f * (1.0f + erff(v * 0.70710678118654752f));
                    if (C)   C[(size_t)(mb + r) * N + n] = v;
                    if (C16) C16[(size_t)(mb + r) * N + n] = f2bf(v);
                }
            }
        }
    } else {
        float* Cp = C + (size_t)blockIdx.z * M * N;
        #pragma unroll
        for (int j = 0; j < 4; ++j) {
            int n = n0 + wn + j * 16 + l15;
            #pragma unroll
            for (int i = 0; i < 4; ++i) {
                int mb = m0 + wm + i * 16 + quad * 4;
                #pragma unroll
                for (int r = 0; r < 4; ++r)
                    Cp[(size_t)(mb + r) * N + n] = acc[i][j][r];
            }
        }
    }
}

// ---------------- qk_pack: RoPE + scale + bf16; optional 2nd partial + bias ----------------
__global__ void qk_pack(const float* __restrict__ x, const float* __restrict__ x2,
                        const float* __restrict__ qb, const float* __restrict__ pos,
                        short* __restrict__ outp, float scale, int ldx, int off)
{
    int idx = blockIdx.x * blockDim.x + threadIdx.x;
    if (idx >= kTok * kH * 32) return;
    int d = idx & 31;
    int h = (idx >> 5) & (kH - 1);
    int row = idx >> 9;
    int l = row & (kL - 1);
    int b = row >> 10;
    float a1 = pos[l * kHD + d];
    float a2 = pos[l * kHD + d + 32];
    size_t base = (size_t)row * ldx + off + h * kHD;
    float x1 = x[base + d], xx2 = x[base + d + 32];
    if (x2) { x1 += x2[base + d]; xx2 += x2[base + d + 32]; }
    if (qb) { x1 += qb[h * kHD + d]; xx2 += qb[h * kHD + d + 32]; }
    float r1 = (x1 * cosf(a1) - xx2 * sinf(a1)) * scale;
    float r2 = (xx2 * cosf(a2) + x1 * sinf(a2)) * scale;
    size_t ob = ((size_t)(b * kH + h) * kL + l) * 64;
    outp[ob + d]      = f2bf(r1);
    outp[ob + d + 32] = f2bf(r2);
}

// ---------------- v_pack: transpose [Tok,ldx] fp32 -> [b,h,hd,l] bf16 ----------------
__global__ __launch_bounds__(256) void v_pack(const float* __restrict__ v, short* __restrict__ outp,
                                              int ldx, int off)
{
    int l0 = blockIdx.x * 64, h = blockIdx.y, b = blockIdx.z;
    __shared__ float t[64][65];
    int tid = threadIdx.x;
    #pragma unroll
    for (int e = 0; e < 4; ++e) {
        int idx = tid + e * 256;
        int r = idx >> 4, c4 = (idx & 15) * 4;
        const float4 vv = *(const float4*)&v[(size_t)(b * kL + l0 + r) * ldx + off + h * kHD + c4];
        t[r][c4] = vv.x; t[r][c4 + 1] = vv.y; t[r][c4 + 2] = vv.z; t[r][c4 + 3] = vv.w;
    }
    __syncthreads();
    int hd = tid >> 2, seg = (tid & 3) * 16;
    size_t ob = ((size_t)(b * kH + h) * 64 + hd) * kL + l0 + seg;
    short tmp[16];
    #pragma unroll
    for (int i = 0; i < 16; ++i) tmp[i] = f2bf(t[seg + i][hd]);
    #pragma unroll
    for (int i = 0; i < 16; i += 4)
        *(short4*)&outp[ob + i] = make_short4(tmp[i], tmp[i + 1], tmp[i + 2], tmp[i + 3]);
}

// ---------------- MFMA flash attention (fragment-ordered LDS, staged alibi; bf16 out) ----------------
constexpr int AQ = 64, AK = 64;
__global__ __launch_bounds__(256, 2) void attn_mfma(
    const short* __restrict__ qpk, const short* __restrict__ kpk,
    const short* __restrict__ vpk, const float* __restrict__ alibi,
    const int* __restrict__ mask, short* __restrict__ out)
{
    const int q0 = blockIdx.x * AQ, h = blockIdx.y, b = blockIdx.z;
    const int tid = threadIdx.x, wave = tid >> 6, lane = tid & 63;
    const int l15 = lane & 15, quad = lane >> 4;
    __shared__ short Qf[4096];
    __shared__ short Kf[4096];
    __shared__ short Vf[4096];
    __shared__ float ALPS[4 * 1088];

    const short* qbase = qpk + ((size_t)(b * kH + h) * kL) * 64;
    const short* kbase = kpk + ((size_t)(b * kH + h) * kL) * 64;
    const short* vbase = vpk + ((size_t)(b * kH + h) * 64) * kL;
    const float* abase = alibi + ((size_t)h * kL + q0) * kL;
    const int*   mbase = mask + b * kL;

    const int sr = tid >> 3, sc8 = (tid & 7) * 8;
    const int sQuad = (sc8 >> 3) & 3, sS = sc8 >> 5;
    const int ar = tid >> 4, ac4 = (tid & 15) * 4;

    #pragma unroll
    for (int e = 0; e < 2; ++e) {
        int r = sr + e * 32;
        int slot = ((r >> 4) * 2 + sS) * 512 + (r & 15) * 32 + sQuad * 8;
        *(bf16x8*)&Qf[slot] = *(const bf16x8*)&qbase[(size_t)(q0 + r) * 64 + sc8];
    }

    bf16x8 rk[2], rv[2];
    float4 ral[4];
    int4 rmk;
    auto load_tile = [&](int k0) {
        #pragma unroll
        for (int e = 0; e < 2; ++e) {
            int r = sr + e * 32;
            rk[e] = *(const bf16x8*)&kbase[(size_t)(k0 + r) * 64 + sc8];
            rv[e] = *(const bf16x8*)&vbase[(size_t)r * kL + k0 + sc8];
        }
        #pragma unroll
        for (int e = 0; e < 4; ++e)
            ral[e] = *(const float4*)&abase[(size_t)(ar + e * 16) * kL + k0 + ac4];
        rmk = *(const int4*)&mbase[k0 + ac4];
    };
    auto store_tile = [&]() {
        #pragma unroll
        for (int e = 0; e < 2; ++e) {
            int r = sr + e * 32;
            int slot = ((r >> 4) * 2 + sS) * 512 + (r & 15) * 32 + sQuad * 8;
            *(bf16x8*)&Kf[slot] = rk[e];
            *(bf16x8*)&Vf[slot] = rv[e];
        }
        #pragma unroll
        for (int e = 0; e < 4; ++e) {
            float4 a = ral[e];
            a.x = rmk.x ? -1e30f : a.x;
            a.y = rmk.y ? -1e30f : a.y;
            a.z = rmk.z ? -1e30f : a.z;
            a.w = rmk.w ? -1e30f : a.w;
            *(float4*)&ALPS[(ar + e * 16) * 68 + ac4] = a;
        }
    };

    float mst[4], lst[4];
    #pragma unroll
    for (int r = 0; r < 4; ++r) { mst[r] = -3e38f; lst[r] = 0.f; }
    f32x4 oacc[4];
    #pragma unroll
    for (int j = 0; j < 4; ++j) oacc[j] = (f32x4){0.f, 0.f, 0.f, 0.f};

    load_tile(0);
    __syncthreads();

    bf16x8 aq[2];
    #pragma unroll
    for (int s = 0; s < 2; ++s)
        aq[s] = *(bf16x8*)&Qf[(wave * 2 + s) * 512 + l15 * 32 + quad * 8];

    for (int t = 0; t < kL / AK; ++t) {
        store_tile();
        __syncthreads();
        if (t + 1 < kL / AK) load_tile((t + 1) * AK);

        f32x4 sacc[4];
        #pragma unroll
        for (int nt = 0; nt < 4; ++nt) sacc[nt] = (f32x4){0.f, 0.f, 0.f, 0.f};
        #pragma unroll
        for (int nt = 0; nt < 4; ++nt)
            #pragma unroll
            for (int s = 0; s < 2; ++s) {
                bf16x8 bk = *(bf16x8*)&Kf[(nt * 2 + s) * 512 + l15 * 32 + quad * 8];
                sacc[nt] = __builtin_amdgcn_mfma_f32_16x16x32_bf16(aq[s], bk, sacc[nt], 0, 0, 0);
            }

        float sv[4][4];
        float mx[4] = {-3e38f, -3e38f, -3e38f, -3e38f};
        #pragma unroll
        for (int nt = 0; nt < 4; ++nt)
            #pragma unroll
            for (int r = 0; r < 4; ++r) {
                float al = ALPS[(wave * 16 + quad * 4 + r) * 68 + nt * 16 + l15];
                float s = sacc[nt][r] + al;
                sv[nt][r] = s;
                mx[r] = fmaxf(mx[r], s);
            }
        #pragma unroll
        for (int m = 1; m <= 8; m <<= 1)
            #pragma unroll
            for (int r = 0; r < 4; ++r)
                mx[r] = fmaxf(mx[r], __shfl_xor(mx[r], m));
        float alpha[4], lsum[4];
        #pragma unroll
        for (int r = 0; r < 4; ++r) {
            float mn = fmaxf(mst[r], mx[r]);
            alpha[r] = __expf(mst[r] - mn);
            mst[r] = mn;
            lsum[r] = 0.f;
        }
        #pragma unroll
        for (int nt = 0; nt < 4; ++nt)
            #pragma unroll
            for (int r = 0; r < 4; ++r) {
                float p = __expf(sv[nt][r] - mst[r]);
                sv[nt][r] = p;
                lsum[r] += p;
            }
        #pragma unroll
        for (int m = 1; m <= 8; m <<= 1)
            #pragma unroll
            for (int r = 0; r < 4; ++r)
                lsum[r] += __shfl_xor(lsum[r], m);
        #pragma unroll
        for (int r = 0; r < 4; ++r) lst[r] = lst[r] * alpha[r] + lsum[r];

        #pragma unroll
        for (int nt = 0; nt < 4; ++nt)
            #pragma unroll
            for (int r = 0; r < 4; ++r)
                ALPS[wave * 1088 + (quad * 4 + r) * 67 + nt * 16 + l15] = sv[nt][r];
        #pragma unroll
        for (int j = 0; j < 4; ++j)
            #pragma unroll
            for (int r = 0; r < 4; ++r)
                oacc[j][r] *= alpha[r];

        #pragma unroll
        for (int s = 0; s < 2; ++s) {
            int pb = wave * 1088 + l15 * 67 + s * 32 + quad * 8;
            bf16x8 ap;
            #pragma unroll
            for (int e = 0; e < 8; ++e) ap[e] = f2bf(ALPS[pb + e]);
            #pragma unroll
            for (int j = 0; j < 4; ++j) {
                bf16x8 bv = *(bf16x8*)&Vf[(j * 2 + s) * 512 + l15 * 32 + quad * 8];
                oacc[j] = __builtin_amdgcn_mfma_f32_16x16x32_bf16(ap, bv, oacc[j], 0, 0, 0);
            }
        }
        __syncthreads();
    }

    #pragma unroll
    for (int j = 0; j < 4; ++j)
        #pragma unroll
        for (int r = 0; r < 4; ++r) {
            int qrow = q0 + wave * 16 + quad * 4 + r;
            out[(size_t)(b * kL + qrow) * kD + h * kHD + j * 16 + l15] = f2bf(oacc[j][r] / lst[r]);
        }
}

extern "C" void kernel_launch(void* const* d_in, const int* in_sizes, int n_in,
                              void* d_out, int out_size, void* d_ws, size_t ws_size,
                              hipStream_t stream)
{
    const float* memory      = (const float*)d_in[0];
    const float* tgt         = (const float*)d_in[1];
    const float* self_alibi  = (const float*)d_in[2];
    const float* self_pos    = (const float*)d_in[3];
    const float* cross_alibi = (const float*)d_in[4];
    const float* cross_pos   = (const float*)d_in[5];
    const int*   mask        = (const int*)d_in[6];
    const float* sa_lat_w = (const float*)d_in[7];   const float* sa_lat_b = (const float*)d_in[8];
    const float* sa_q_w   = (const float*)d_in[9];   const float* sa_q_b   = (const float*)d_in[10];
    const float* sa_k_w   = (const float*)d_in[11];  const float* sa_k_b   = (const float*)d_in[12];
    const float* sa_v_w   = (const float*)d_in[13];  const float* sa_v_b   = (const float*)d_in[14];
    const float* sa_out_w = (const float*)d_in[15];  const float* sa_out_b = (const float*)d_in[16];
    const float* ca_lat_w = (const float*)d_in[17];  const float* ca_lat_b = (const float*)d_in[18];
    const float* ca_q_w   = (const float*)d_in[19];  const float* ca_q_b   = (const float*)d_in[20];
    const float* ca_k_w   = (const float*)d_in[21];  const float* ca_k_b   = (const float*)d_in[22];
    const float* ca_v_w   = (const float*)d_in[23];  const float* ca_v_b   = (const float*)d_in[24];
    const float* ca_out_w = (const float*)d_in[25];  const float* ca_out_b = (const float*)d_in[26];
    const float* lin1_w   = (const float*)d_in[27];  const float* lin1_b   = (const float*)d_in[28];
    const float* lin2_w   = (const float*)d_in[29];  const float* lin2_b   = (const float*)d_in[30];
    const float* n1_g = (const float*)d_in[31];  const float* n1_b = (const float*)d_in[32];
    const float* n2_g = (const float*)d_in[33];  const float* n2_b = (const float*)d_in[34];
    const float* n3_g = (const float*)d_in[35];  const float* n3_b = (const float*)d_in[36];

    // workspace map (floats; M1 = 1M floats = 4 MB). Total 15M floats = 60 MB.
    const size_t M1 = 1u << 20;
    float* W      = (float*)d_ws;
    float* xb     = W;                              // 0-2M   residual fp32
    short* tgt16  = (short*)W;                      // 0-0.5M  (dead before xb written)
    short* mem16  = (short*)(W + 2 * M1);           // 2M-2.5M
    float* PL     = W + 2 * M1;                     // 2M-6M  lin2 partials [2][2048][1024] (FFN phase)
    short* xb16   = (short*)(W + 4 * M1);           // 4M-5M  (dead after lin1 -> PL may clobber)
    short* qpk    = (short*)(W + 5 * M1);           // 5M-6M
    short* proj16 = (short*)(W + 6 * M1);           // 6M-6.5M
    float* qkvb   = W + 6 * M1 + M1 / 2;            // 6.5M-12.5M fused qkv fp32
    short* attnb16= (short*)(W + 6 * M1 + M1 / 2);  // 6.5M-7.5M (qkvb dead during attn)
    short* ffh16  = (short*)(W + 7 * M1 + M1 / 2);  // 7.5M-11.5M FFN hidden bf16
    float* PP     = W + 8 * M1 + M1 / 2;            // 8.5M-12.5M partials (lat S=4 / out,caq S=2) & kvb
    float* kvb    = W + 8 * M1 + M1 / 2;            // 8.5M-12.5M cross k|v fp32 [2048][2048]
    short* wslot  = (short*)(W + 12 * M1 + M1 / 2); // 12.5M-14.5M transposed weights
    short* kpk    = (short*)(W + 12 * M1 + M1 / 2); // 12.5M-13.5M (wslot dead during packs/attn)
    short* vpk    = (short*)(W + 13 * M1 + M1 / 2); // 13.5M-14.5M
    float* bcat   = W + 14 * M1 + M1 / 2;           // 14.5M+ bias concat scratch

    auto gemm = [&](const short* A, const float* Wt, const float* bias, float* C, short* C16,
                    int M, int N, int K, int act, int S) {
        transpose_bf16<<<dim3(N / 32, K / 32), dim3(256), 0, stream>>>(Wt, wslot, K, N);
        gemm_mfma<<<dim3(N / 128, M / 128, S), dim3(256), 0, stream>>>(A, wslot, bias, C, C16, M, N, K, act, S);
    };
    dim3 agrid(kL / AQ, kH, kB);
    dim3 vgrid(kL / 64, kH, kB);
    dim3 tgD(kD / 32, kP / 32);
    const size_t strD = (size_t)kTok * kD;   // partial stride for N=1024
    const size_t strP = (size_t)kTok * kP;   // partial stride for N=512

    // ---- self attention ----
    cast_bf16<<<dim3(2048), dim3(256), 0, stream>>>(tgt, tgt16, kTok * kD / 4);
    gemm(tgt16, sa_lat_w, sa_lat_b, PP, nullptr, kTok, kP, kD, 0, 4);
    reduce4_cast<<<dim3(1024), dim3(256), 0, stream>>>(PP, strP, sa_lat_b, proj16, kTok * kP / 4, kP);
    transpose_bf16<<<tgD, dim3(256), 0, stream>>>(sa_q_w, wslot, kP, kD);
    transpose_bf16<<<tgD, dim3(256), 0, stream>>>(sa_k_w, wslot + (size_t)kD * kP, kP, kD);
    transpose_bf16<<<tgD, dim3(256), 0, stream>>>(sa_v_w, wslot + (size_t)2 * kD * kP, kP, kD);
    concat_bias<<<dim3(12), dim3(256), 0, stream>>>(bcat, sa_q_b, sa_k_b, sa_v_b, kD);
    gemm_mfma<<<dim3(3 * kD / 128, kTok / 128, 1), dim3(256), 0, stream>>>(
        proj16, wslot, bcat, qkvb, nullptr, kTok, 3 * kD, kP, 0, 1);
    qk_pack<<<dim3(4096), dim3(256), 0, stream>>>(qkvb, nullptr, nullptr, self_pos, qpk, 0.125f, 3 * kD, 0);
    qk_pack<<<dim3(4096), dim3(256), 0, stream>>>(qkvb, nullptr, nullptr, self_pos, kpk, 1.0f, 3 * kD, kD);
    v_pack<<<vgrid, dim3(256), 0, stream>>>(qkvb, vpk, 3 * kD, 2 * kD);
    attn_mfma<<<agrid, dim3(256), 0, stream>>>(qpk, kpk, vpk, self_alibi, mask, attnb16);
    gemm(attnb16, sa_out_w, sa_out_b, PP, nullptr, kTok, kD, kD, 0, 2);
    add_ln2<<<dim3(kTok), dim3(256), 0, stream>>>(tgt, PP, strD, sa_out_b, n1_g, n1_b, xb, xb16);

    // ---- cross attention ----
    cast_bf16<<<dim3(2048), dim3(256), 0, stream>>>(memory, mem16, kTok * kD / 4);
    gemm(mem16, ca_lat_w, ca_lat_b, PP, nullptr, kTok, kP, kD, 0, 4);
    reduce4_cast<<<dim3(1024), dim3(256), 0, stream>>>(PP, strP, ca_lat_b, proj16, kTok * kP / 4, kP);
    gemm(xb16, ca_q_w, ca_q_b, PP, nullptr, kTok, kD, kD, 0, 2);
    qk_pack<<<dim3(4096), dim3(256), 0, stream>>>(PP, PP + strD, ca_q_b, cross_pos, qpk, 0.125f, kD, 0);
    transpose_bf16<<<tgD, dim3(256), 0, stream>>>(ca_k_w, wslot, kP, kD);
    transpose_bf16<<<tgD, dim3(256), 0, stream>>>(ca_v_w, wslot + (size_t)kD * kP, kP, kD);
    concat_bias<<<dim3(8), dim3(256), 0, stream>>>(bcat, ca_k_b, ca_v_b, nullptr, kD);
    gemm_mfma<<<dim3(2 * kD / 128, kTok / 128, 1), dim3(256), 0, stream>>>(
        proj16, wslot, bcat, kvb, nullptr, kTok, 2 * kD, kP, 0, 1);
    qk_pack<<<dim3(4096), dim3(256), 0, stream>>>(kvb, nullptr, nullptr, cross_pos, kpk, 1.0f, 2 * kD, 0);
    v_pack<<<vgrid, dim3(256), 0, stream>>>(kvb, vpk, 2 * kD, kD);
    attn_mfma<<<agrid, dim3(256), 0, stream>>>(qpk, kpk, vpk, cross_alibi, mask, attnb16);
    gemm(attnb16, ca_out_w, ca_out_b, PP, nullptr, kTok, kD, kD, 0, 2);
    add_ln2<<<dim3(kTok), dim3(256), 0, stream>>>(xb, PP, strD, ca_out_b, n2_g, n2_b, xb, xb16);

    // ---- FFN ----
    gemm(xb16, lin1_w, lin1_b, nullptr, ffh16, kTok, kFF, kD, 1, 1);
    gemm(ffh16, lin2_w, lin2_b, PL, nullptr, kTok, kD, kFF, 0, 2);
    ln_final2<<<dim3(kTok), dim3(256), 0, stream>>>(xb, PL, strD, lin2_b, n3_g, n3_b, (float*)d_out);
}